// Round 15
// baseline (100.168 us; speedup 1.0000x reference)
//
#include <hip/hip_runtime.h>
#include <hip/hip_bf16.h>
#include <cstdint>

typedef __attribute__((ext_vector_type(4)))  float f32x4;
typedef __attribute__((ext_vector_type(16))) float f32x16;
typedef __attribute__((ext_vector_type(8)))  short s16x8;

#define LOG2E 1.4426950408889634f
#define MFIX  64.0f              // fixed softmax max: exp(S-64); safe for S in (-23, 152)

#define B_   4
#define C_   256
#define N_   4096
#define NT_  256
#define MB_  128
#define QG_  128

// workspace byte offsets
#define WS_WFRAG 0u
#define WS_BIAS  163840u
#define WS_Q     262144u
#define WS_K     1310720u
#define WS_V     2359296u
#define WS_PART  11534336u   // 512 qtiles * 4 splits * 8192 bf16 = 32 MiB
#define WS_ML    45088768u   // 2048 * 64 f32
#define WS_NEED  45613056ull

__device__ __forceinline__ short bf16s(float f) {
  return (short)__bfloat16_as_ushort(__float2bfloat16(f));
}
__device__ __forceinline__ float bf2f(short h) {
  union { unsigned u; float f; } v; v.u = ((unsigned)(unsigned short)h) << 16;
  return v.f;
}
__device__ __forceinline__ void gl_lds16(const void* g, void* l) {
  __builtin_amdgcn_global_load_lds(
      (const __attribute__((address_space(1))) unsigned int*)g,
      (__attribute__((address_space(3))) unsigned int*)l, 16, 0, 0);
}

// ---------------- pack W (320x256) into A-frag layout (16x16x32), gather bias ----------------
__global__ void wprep_kernel(const float* __restrict__ Wq, const float* __restrict__ Wk,
                             const float* __restrict__ Wv, const float* __restrict__ bq,
                             const float* __restrict__ bk, const float* __restrict__ bv,
                             short* __restrict__ wfrag, float* __restrict__ bias) {
  int d0 = blockIdx.x * 256 + threadIdx.x;
  int d = d0;
  int j  = d & 7;  d >>= 3;
  int c  = d & 15; d >>= 4;
  int g  = d & 3;  d >>= 2;
  int ks = d & 7;  d >>= 3;
  int t  = d;
  int o  = t * 16 + c;
  int ch = ks * 32 + g * 8 + j;
  float w = (o < 32) ? Wq[o * 256 + ch] : (o < 64) ? Wk[(o - 32) * 256 + ch]
                                                   : Wv[(o - 64) * 256 + ch];
  wfrag[d0] = bf16s(w);
  if (d0 < 320) bias[d0] = (d0 < 32) ? bq[d0] : (d0 < 64) ? bk[d0 - 32] : bv[d0 - 64];
}

// ---------------- fused QKV projection (MFMA) + inline gate + 32x32-frag stores ----------------
__global__ __launch_bounds__(256) void proj_kernel(
    const float* __restrict__ x, const short* __restrict__ wfrag,
    const float* __restrict__ bias, const float* __restrict__ gm,
    short* __restrict__ qs, short* __restrict__ ksz, short* __restrict__ vs) {
  int b = blockIdx.x >> 8, nt = blockIdx.x & 255;
  int lane = threadIdx.x & 63, wave = threadIdx.x >> 6;
  int g = lane >> 4, c = lane & 15;
  int n = nt * 16 + c;

  float gt;
  {
    int y = n >> 6, xp = n & 63;
    float fy = (float)(y * 31) / 63.0f;
    float fx = (float)(xp * 31) / 63.0f;
    int y0 = (int)fy, x0 = (int)fx;
    float wy = fy - (float)y0, wx = fx - (float)x0;
    int y1 = min(y0 + 1, 31), x1 = min(x0 + 1, 31);
    const float* p = gm + b * 1024;
    float v00 = p[y0 * 32 + x0], v01 = p[y0 * 32 + x1];
    float v10 = p[y1 * 32 + x0], v11 = p[y1 * 32 + x1];
    float top = v00 * (1.f - wx) + v01 * wx;
    float bot = v10 * (1.f - wx) + v11 * wx;
    float gv  = top * (1.f - wy) + bot * wy;
    gt = 1.0f + 1.0f / (1.0f + expf(-gv));
  }

  const float* xb = x + b * (C_ * N_) + n;
  s16x8 xf[8];
  #pragma unroll
  for (int ks = 0; ks < 8; ++ks) {
    int ch0 = ks * 32 + g * 8;
    s16x8 v;
    #pragma unroll
    for (int j = 0; j < 8; ++j) v[j] = bf16s(xb[(ch0 + j) * N_]);
    xf[ks] = v;
  }

  int qt32 = n >> 5, r = n & 31;
  for (int t = wave * 5; t < wave * 5 + 5; ++t) {
    f32x4 acc = {0.f, 0.f, 0.f, 0.f};
    #pragma unroll
    for (int ks = 0; ks < 8; ++ks) {
      s16x8 wf = *(const s16x8*)(wfrag + ((((t * 8 + ks) * 4 + g) * 16 + c) * 8));
      acc = __builtin_amdgcn_mfma_f32_16x16x32_bf16(wf, xf[ks], acc, 0, 0, 0);
    }
    #pragma unroll
    for (int jj = 0; jj < 4; ++jj) {
      int o = t * 16 + g * 4 + jj;
      float val = (acc[jj] + bias[o]) * gt;
      short bv16 = bf16s(val);
      if (o < 64) {
        int ch = o & 31;
        int s  = (ch >> 4) & 1, hi = (ch >> 3) & 1, j = ch & 7;
        short* dst = (o < 32) ? qs : ksz;
        dst[(((b * QG_ + qt32) * 2 + s) * 64 + hi * 32 + r) * 8 + j] = bv16;
      } else {
        int cv = o - 64;
        int ct = cv >> 5, lam = cv & 31;
        int s  = (r >> 4) & 1, r4 = r & 15;
        int k  = (r4 & 3) | (((r4 >> 3) & 1) << 2) | (((r4 >> 2) & 1) << 3);
        int hi = k >> 3, j = k & 7;
        vs[((((size_t)(b * MB_ + qt32) * 8 + ct) * 2 + s) * 64 + hi * 32 + lam) * 8 + j] = bv16;
      }
    }
  }
}

// ---- attn v10: P shared via LDS, 2-barrier/3-buffer discipline (v5 loop), 4 waves/SIMD ----
// 512 blocks x 512 thr (8 waves; 2 blocks/CU). Block: batch b, 4 q-tiles, kv quarter s.
// Wave (qi,h): h0 computes QK(j+1)+softmax once, writes P to LDS (parity buffers);
// both waves PV their channel half with P(j). Buffer rotation bc/bn/bs with stage
// between B1 and B2 (restage always barrier-separated from last reader — v5-proven).
__global__ __launch_bounds__(512, 4) void attn_split_kernel(
    const short* __restrict__ qs, const short* __restrict__ ksz,
    const short* __restrict__ vs, short* __restrict__ part,
    float* __restrict__ mlbuf) {
  __shared__ __align__(16) short k_lds[3][1024];      // 3 x 2KB
  __shared__ __align__(16) short v_lds[3][8192];      // 3 x 16KB
  __shared__ __align__(16) short p_lds[2][4][2][512]; // 2 bufs x 4 qt x 2 frags x 1KB

  int bid = blockIdx.x;
  int b  = (bid & 7) >> 1;                         // batch pinned to XCD pair
  int u  = ((bid >> 3) << 1) | (bid & 1);          // 0..127
  int qb = u >> 2, s = u & 3;
  int tid = threadIdx.x, lane = tid & 63, wave = tid >> 6;
  int qi = wave >> 1, h = wave & 1;
  int lq = lane & 31, hi = lane >> 5;
  int qt = qb * 4 + qi;

  const short* qbp = qs + (size_t)(((b * QG_ + qt) * 2) * 64 + lane) * 8;
  s16x8 qf0 = *(const s16x8*)(qbp);
  s16x8 qf1 = *(const s16x8*)(qbp + 512);
  asm volatile("s_waitcnt vmcnt(0)" ::: "memory");   // zero vm counter

  f32x16 acc[4];
  #pragma unroll
  for (int ct = 0; ct < 4; ++ct)
    #pragma unroll
    for (int e = 0; e < 16; ++e) acc[ct][e] = 0.f;
  float lsum = 0.f;

  const char* kbase = (const char*)(ksz + (size_t)b * (MB_ * 1024));
  const char* vbase = (const char*)(vs + (size_t)b * ((size_t)MB_ * 8192));

  // stage tile mb into buf nb: V 16KB (2 loads/thread), K 2KB (tid<128, 1 load)
  #define STAGE(mb, nb)                                                          \
    {                                                                            \
      const char* vsrc = vbase + (size_t)(mb) * 16384;                           \
      gl_lds16(vsrc + tid * 16,        &v_lds[nb][tid * 8]);                     \
      gl_lds16(vsrc + 8192 + tid * 16, &v_lds[nb][4096 + tid * 8]);              \
      if (tid < 128) {                                                           \
        const char* ksrc = kbase + (size_t)(mb) * 2048;                          \
        gl_lds16(ksrc + tid * 16, &k_lds[nb][tid * 8]);                          \
      }                                                                          \
    }
  #define WAIT_PREV()                                                            \
    {                                                                            \
      if (wave < 2) asm volatile("s_waitcnt vmcnt(3)" ::: "memory");             \
      else          asm volatile("s_waitcnt vmcnt(2)" ::: "memory");             \
    }
  // B1: flush own LDS ops (incl. h0's P write) then barrier
  #define BARRIER_LGKM() asm volatile("s_waitcnt lgkmcnt(0)\n\ts_barrier" ::: "memory")
  #define BARRIER_RAW()  asm volatile("s_barrier" ::: "memory")

  s16x8 pf0, pf1;    // P consumed by PV (read from LDS)
  s16x8 ps0, ps1;    // P produced by softmax (h0 only)
  f32x16 st;

  #define QKT(buf)                                                               \
    {                                                                            \
      const short* kb = k_lds[buf];                                              \
      s16x8 kf0 = *(const s16x8*)(kb + lane * 8);                                \
      s16x8 kf1 = *(const s16x8*)(kb + 512 + lane * 8);                          \
      _Pragma("unroll")                                                          \
      for (int e = 0; e < 16; ++e) st[e] = 0.f;                                  \
      st = __builtin_amdgcn_mfma_f32_32x32x16_bf16(kf0, qf0, st, 0, 0, 0);       \
      st = __builtin_amdgcn_mfma_f32_32x32x16_bf16(kf1, qf1, st, 0, 0, 0);       \
    }

  #define SOFTMAX()                                                              \
    {                                                                            \
      float psum = 0.f;                                                          \
      _Pragma("unroll")                                                          \
      for (int j = 0; j < 8; ++j) {                                              \
        float p = exp2f((st[j] - MFIX) * LOG2E);                                 \
        psum += p; ps0[j] = bf16s(p);                                            \
      }                                                                          \
      _Pragma("unroll")                                                          \
      for (int j = 0; j < 8; ++j) {                                              \
        float p = exp2f((st[8 + j] - MFIX) * LOG2E);                             \
        psum += p; ps1[j] = bf16s(p);                                            \
      }                                                                          \
      lsum += psum;                                                              \
    }

  #define PREAD(jpar)                                                            \
    {                                                                            \
      pf0 = *(const s16x8*)&p_lds[jpar][qi][0][lane * 8];                        \
      pf1 = *(const s16x8*)&p_lds[jpar][qi][1][lane * 8];                        \
    }
  #define PWRITE(jpar)                                                           \
    {                                                                            \
      *(s16x8*)&p_lds[jpar][qi][0][lane * 8] = ps0;                              \
      *(s16x8*)&p_lds[jpar][qi][1][lane * 8] = ps1;                              \
    }

  // PV on this wave's channel half: global ct = h*4 + ctl
  #define PVACC(buf)                                                             \
    {                                                                            \
      const short* vb = v_lds[buf] + h * 4096;                                   \
      _Pragma("unroll")                                                          \
      for (int ctl = 0; ctl < 4; ++ctl) {                                        \
        s16x8 vf0 = *(const s16x8*)(vb + (ctl * 2 + 0) * 512 + lane * 8);        \
        s16x8 vf1 = *(const s16x8*)(vb + (ctl * 2 + 1) * 512 + lane * 8);        \
        acc[ctl] = __builtin_amdgcn_mfma_f32_32x32x16_bf16(vf0, pf0, acc[ctl], 0, 0, 0); \
        acc[ctl] = __builtin_amdgcn_mfma_f32_32x32x16_bf16(vf1, pf1, acc[ctl], 0, 0, 0); \
      }                                                                          \
    }

  int base = s * 32;
  // ---- prologue: stage tiles 0,1; h0 computes P(0), publishes ----
  STAGE(base + 0, 0);
  STAGE(base + 1, 1);
  WAIT_PREV();
  BARRIER_LGKM();
  if (h == 0) {
    QKT(0);
    SOFTMAX();
    PWRITE(0);
  }

  int bc = 0, bn = 1, bs = 2;
  for (int j = 0; j < 32; ++j) {
    BARRIER_LGKM();                        // B1: readers of bs done; h0's P(j) write flushed
    int jn = j + 2; if (jn > 31) jn = 31;  // tail duplicate stage is benign
    STAGE(base + jn, bs);
    WAIT_PREV();                           // tile j+1 landed (own); j+2 in flight
    BARRIER_RAW();                         // B2: all waves' tile j+1 landed; P(j) visible
    PREAD(j & 1);                          // P(j)
    if (h == 0) {
      __builtin_amdgcn_s_setprio(1);
      if (j < 31) QKT(bn);                 // S(j+1)
      PVACC(bc);                           // O += V(j) P(j)
      __builtin_amdgcn_s_setprio(0);
      if (j < 31) {
        SOFTMAX();                         // P(j+1)
        PWRITE((j + 1) & 1);
      }
    } else {
      __builtin_amdgcn_s_setprio(1);
      PVACC(bc);
      __builtin_amdgcn_s_setprio(0);
    }
    int t = bc; bc = bn; bn = bs; bs = t;
  }

  // fold the two half-lanes' key sets once (h0 holds the true lsum)
  lsum += __shfl_xor(lsum, 32);

  // ---- write partial: l (f32, h0) + acc half (bf16) ----
  int pt = (b * 128 + qt) * 4 + s;
  if (h == 0 && lane < 32) mlbuf[pt * 64 + lq] = lsum;
  short* pb = part + (size_t)pt * 8192 + h * 4096;
  #pragma unroll
  for (int ctl = 0; ctl < 4; ++ctl)
    #pragma unroll
    for (int e = 0; e < 16; ++e) {
      int CH = ctl * 32 + (e & 3) + 8 * (e >> 2) + 4 * hi;   // local 0..127
      pb[CH * 32 + lq] = bf16s(acc[ctl][e]);
    }
  #undef STAGE
  #undef WAIT_PREV
  #undef BARRIER_LGKM
  #undef BARRIER_RAW
  #undef QKT
  #undef SOFTMAX
  #undef PREAD
  #undef PWRITE
  #undef PVACC
}

// ---------------- combine: plain sum over 4 kv-splits (shared fixed max), residual ----------
__global__ __launch_bounds__(256) void combine_kernel(
    const short* __restrict__ part, const float* __restrict__ mlbuf,
    const float* __restrict__ x, const float* __restrict__ gamma,
    float* __restrict__ out) {
  int bid = blockIdx.x;
  int b = bid >> 7, qt = bid & 127;
  int t = threadIdx.x;
  int q = t & 31, cg = t >> 5;
  int base = (b * 128 + qt) * 4;
  float L = mlbuf[(base + 0) * 64 + q] + mlbuf[(base + 1) * 64 + q]
          + mlbuf[(base + 2) * 64 + q] + mlbuf[(base + 3) * 64 + q];
  float rn = gamma[0] / L;
  int n = qt * 32 + q;
  const short* p0 = part + (size_t)(base + 0) * 8192;
  const short* p1 = part + (size_t)(base + 1) * 8192;
  const short* p2 = part + (size_t)(base + 2) * 8192;
  const short* p3 = part + (size_t)(base + 3) * 8192;
  #pragma unroll 4
  for (int cc = 0; cc < 32; ++cc) {
    int ch = cg * 32 + cc;
    int off = ch * 32 + q;
    float o = bf2f(p0[off]) + bf2f(p1[off]) + bf2f(p2[off]) + bf2f(p3[off]);
    int idx = (b * C_ + ch) * N_ + n;
    out[idx] = rn * o + x[idx];
  }
}

// ---------------- fallback attn (register-V, fixed-max, no workspace partials) --------
__global__ __launch_bounds__(256, 2) void attn_reg_kernel(
    const short* __restrict__ qs, const short* __restrict__ ksz,
    const short* __restrict__ vs, const float* __restrict__ x,
    const float* __restrict__ gamma, float* __restrict__ out) {
  __shared__ float comb_l[4][32];
  __shared__ float sumbuf[4][16][4][64];

  int bid = blockIdx.x;
  int b  = (bid & 7) >> 1;
  int qg = ((bid >> 3) << 1) | (bid & 1);
  int tid = threadIdx.x, lane = tid & 63, wave = tid >> 6;
  int lq = lane & 31;

  const short* qb = qs + (size_t)(((b * QG_ + qg) * 2) * 64 + lane) * 8;
  s16x8 qf0 = *(const s16x8*)(qb);
  s16x8 qf1 = *(const s16x8*)(qb + 512);

  f32x16 acc[8];
  #pragma unroll
  for (int ct = 0; ct < 8; ++ct)
    #pragma unroll
    for (int e = 0; e < 16; ++e) acc[ct][e] = 0.f;
  float lsum = 0.f;

  const short* kb0 = ksz + (size_t)b * (MB_ * 1024) + lane * 8;
  const short* vb0 = vs  + (size_t)b * ((size_t)MB_ * 8192) + lane * 8;

  int mb = wave;
  s16x8 kf0 = *(const s16x8*)(kb0 + mb * 1024);
  s16x8 kf1 = *(const s16x8*)(kb0 + mb * 1024 + 512);

  for (int i = 0; i < 32; ++i) {
    const short* vb = vb0 + (size_t)mb * 8192;
    s16x8 vf[16];
    #pragma unroll
    for (int t = 0; t < 16; ++t) vf[t] = *(const s16x8*)(vb + t * 512);

    f32x16 st;
    #pragma unroll
    for (int e = 0; e < 16; ++e) st[e] = 0.f;
    st = __builtin_amdgcn_mfma_f32_32x32x16_bf16(kf0, qf0, st, 0, 0, 0);
    st = __builtin_amdgcn_mfma_f32_32x32x16_bf16(kf1, qf1, st, 0, 0, 0);

    int mbn = (i < 31) ? (mb + 4) : wave;
    s16x8 nk0 = *(const s16x8*)(kb0 + mbn * 1024);
    s16x8 nk1 = *(const s16x8*)(kb0 + mbn * 1024 + 512);

    float psum = 0.f;
    s16x8 pf0, pf1;
    #pragma unroll
    for (int j = 0; j < 8; ++j) {
      float p = exp2f((st[j] - MFIX) * LOG2E);
      psum += p; pf0[j] = bf16s(p);
    }
    #pragma unroll
    for (int j = 0; j < 8; ++j) {
      float p = exp2f((st[8 + j] - MFIX) * LOG2E);
      psum += p; pf1[j] = bf16s(p);
    }
    lsum += psum;

    #pragma unroll
    for (int ct = 0; ct < 8; ++ct) {
      acc[ct] = __builtin_amdgcn_mfma_f32_32x32x16_bf16(vf[ct * 2],     pf0, acc[ct], 0, 0, 0);
      acc[ct] = __builtin_amdgcn_mfma_f32_32x32x16_bf16(vf[ct * 2 + 1], pf1, acc[ct], 0, 0, 0);
    }
    kf0 = nk0; kf1 = nk1; mb = mbn;
  }

  lsum += __shfl_xor(lsum, 32);
  if (lane < 32) comb_l[wave][lq] = lsum;
  __syncthreads();
  float L = comb_l[0][lq] + comb_l[1][lq] + comb_l[2][lq] + comb_l[3][lq];
  float rn = gamma[0] / L;
  int n = qg * 32 + lq;
  int hi = lane >> 5;

  for (int phase = 0; phase < 2; ++phase) {
    #pragma unroll
    for (int t = 0; t < 4; ++t)
      #pragma unroll
      for (int e = 0; e < 16; ++e)
        sumbuf[t][e][wave][lane] = acc[phase * 4 + t][e];
    __syncthreads();
    int ct = phase * 4 + wave;
    #pragma unroll
    for (int e = 0; e < 16; ++e) {
      float ssum = sumbuf[wave][e][0][lane] + sumbuf[wave][e][1][lane]
                 + sumbuf[wave][e][2][lane] + sumbuf[wave][e][3][lane];
      int ch = ct * 32 + (e & 3) + 8 * (e >> 2) + 4 * hi;
      int idx = (b * C_ + ch) * N_ + n;
      out[idx] = rn * ssum + x[idx];
    }
    __syncthreads();
  }
}

extern "C" void kernel_launch(void* const* d_in, const int* in_sizes, int n_in,
                              void* d_out, int out_size, void* d_ws, size_t ws_size,
                              hipStream_t stream) {
  const float* x     = (const float*)d_in[0];
  const float* gm    = (const float*)d_in[1];
  const float* Wq    = (const float*)d_in[2];
  const float* bq    = (const float*)d_in[3];
  const float* Wk    = (const float*)d_in[4];
  const float* bk    = (const float*)d_in[5];
  const float* Wv    = (const float*)d_in[6];
  const float* bv    = (const float*)d_in[7];
  const float* gamma = (const float*)d_in[8];

  char*  ws    = (char*)d_ws;
  short* wfrag = (short*)(ws + WS_WFRAG);
  float* bias  = (float*)(ws + WS_BIAS);
  short* qs    = (short*)(ws + WS_Q);
  short* ksz   = (short*)(ws + WS_K);
  short* vs    = (short*)(ws + WS_V);
  float* out   = (float*)d_out;

  wprep_kernel<<<dim3(320), dim3(256), 0, stream>>>(Wq, Wk, Wv, bq, bk, bv, wfrag, bias);
  proj_kernel<<<dim3(1024), dim3(256), 0, stream>>>(x, wfrag, bias, gm, qs, ksz, vs);

  if (ws_size >= WS_NEED) {
    short* part  = (short*)(ws + WS_PART);
    float* mlbuf = (float*)(ws + WS_ML);
    attn_split_kernel<<<dim3(512), dim3(512), 0, stream>>>(qs, ksz, vs, part, mlbuf);
    combine_kernel<<<dim3(512), dim3(256), 0, stream>>>(part, mlbuf, x, gamma, out);
  } else {
    attn_reg_kernel<<<dim3(512), dim3(256), 0, stream>>>(qs, ksz, vs, x, gamma, out);
  }
}

// Round 16
// 86.356 us; speedup vs baseline: 1.1599x; 1.1599x over previous
//
#include <hip/hip_runtime.h>
#include <hip/hip_bf16.h>
#include <cstdint>

typedef __attribute__((ext_vector_type(4)))  float f32x4;
typedef __attribute__((ext_vector_type(16))) float f32x16;
typedef __attribute__((ext_vector_type(8)))  short s16x8;

#define LOG2E 1.4426950408889634f
#define MFIX  64.0f              // fixed softmax max: exp(S-64); safe for S in (-23, 152)

#define B_   4
#define C_   256
#define N_   4096
#define NT_  256
#define MB_  128
#define QG_  128

// workspace byte offsets
#define WS_WFRAG 0u
#define WS_BIAS  163840u
#define WS_Q     262144u
#define WS_K     1310720u
#define WS_V     2359296u
#define WS_PART  11534336u   // 512 qtiles * 4 splits * 8192 bf16 = 32 MiB
#define WS_ML    45088768u   // 2048 * 64 f32
#define WS_NEED  45613056ull

__device__ __forceinline__ short bf16s(float f) {
  return (short)__bfloat16_as_ushort(__float2bfloat16(f));
}
__device__ __forceinline__ float bf2f(short h) {
  union { unsigned u; float f; } v; v.u = ((unsigned)(unsigned short)h) << 16;
  return v.f;
}
__device__ __forceinline__ float bflo(unsigned u) {
  union { unsigned x; float f; } v; v.x = u << 16; return v.f;
}
__device__ __forceinline__ float bfhi(unsigned u) {
  union { unsigned x; float f; } v; v.x = u & 0xffff0000u; return v.f;
}
__device__ __forceinline__ void gl_lds16(const void* g, void* l) {
  __builtin_amdgcn_global_load_lds(
      (const __attribute__((address_space(1))) unsigned int*)g,
      (__attribute__((address_space(3))) unsigned int*)l, 16, 0, 0);
}

// ---------------- pack W (320x256) into A-frag layout (16x16x32), gather bias ----------------
__global__ void wprep_kernel(const float* __restrict__ Wq, const float* __restrict__ Wk,
                             const float* __restrict__ Wv, const float* __restrict__ bq,
                             const float* __restrict__ bk, const float* __restrict__ bv,
                             short* __restrict__ wfrag, float* __restrict__ bias) {
  int d0 = blockIdx.x * 256 + threadIdx.x;
  int d = d0;
  int j  = d & 7;  d >>= 3;
  int c  = d & 15; d >>= 4;
  int g  = d & 3;  d >>= 2;
  int ks = d & 7;  d >>= 3;
  int t  = d;
  int o  = t * 16 + c;
  int ch = ks * 32 + g * 8 + j;
  float w = (o < 32) ? Wq[o * 256 + ch] : (o < 64) ? Wk[(o - 32) * 256 + ch]
                                                   : Wv[(o - 64) * 256 + ch];
  wfrag[d0] = bf16s(w);
  if (d0 < 320) bias[d0] = (d0 < 32) ? bq[d0] : (d0 < 64) ? bk[d0 - 32] : bv[d0 - 64];
}

// ------- fused QKV projection (MFMA) + inline gate + LDS transpose + coalesced stores -------
// Per block (b, nt): 16 pixels, 320 out-channels. Compute into LDS tiles, then
// cooperative 16B/8B stores into the same fragment layouts as before (bit-identical):
//  Q/K: (((b*QG+qt32)*2+s)*64 + hi*32 + r)*8 + j,  s/hi/j from ch, r = pixel
//  V:   ((((b*MB+mb)*8+ct)*2+s)*64 + hi*32 + lam)*8 + j, ct/lam from ch, s/hi/j from pixel
// Per block: s = nt&1, mb = qt32 = nt>>1, r4 = c (verified identities).
__global__ __launch_bounds__(256) void proj_kernel(
    const float* __restrict__ x, const short* __restrict__ wfrag,
    const float* __restrict__ bias, const float* __restrict__ gm,
    short* __restrict__ qs, short* __restrict__ ksz, short* __restrict__ vs) {
  __shared__ __align__(16) short qk_tile[16][72];   // [px][o 0..63], padded
  __shared__ __align__(16) short v_tile[256][20];   // [cv][px 0..15], padded

  int b = blockIdx.x >> 8, nt = blockIdx.x & 255;
  int tid = threadIdx.x;
  int lane = tid & 63, wave = tid >> 6;
  int g = lane >> 4, c = lane & 15;
  int n = nt * 16 + c;

  float gt;
  {
    int y = n >> 6, xp = n & 63;
    float fy = (float)(y * 31) / 63.0f;
    float fx = (float)(xp * 31) / 63.0f;
    int y0 = (int)fy, x0 = (int)fx;
    float wy = fy - (float)y0, wx = fx - (float)x0;
    int y1 = min(y0 + 1, 31), x1 = min(x0 + 1, 31);
    const float* p = gm + b * 1024;
    float v00 = p[y0 * 32 + x0], v01 = p[y0 * 32 + x1];
    float v10 = p[y1 * 32 + x0], v11 = p[y1 * 32 + x1];
    float top = v00 * (1.f - wx) + v01 * wx;
    float bot = v10 * (1.f - wx) + v11 * wx;
    float gv  = top * (1.f - wy) + bot * wy;
    gt = 1.0f + 1.0f / (1.0f + expf(-gv));
  }

  const float* xb = x + b * (C_ * N_) + n;
  s16x8 xf[8];
  #pragma unroll
  for (int ks = 0; ks < 8; ++ks) {
    int ch0 = ks * 32 + g * 8;
    s16x8 v;
    #pragma unroll
    for (int j = 0; j < 8; ++j) v[j] = bf16s(xb[(ch0 + j) * N_]);
    xf[ks] = v;
  }

  for (int t = wave * 5; t < wave * 5 + 5; ++t) {
    f32x4 acc = {0.f, 0.f, 0.f, 0.f};
    #pragma unroll
    for (int ks = 0; ks < 8; ++ks) {
      s16x8 wf = *(const s16x8*)(wfrag + ((((t * 8 + ks) * 4 + g) * 16 + c) * 8));
      acc = __builtin_amdgcn_mfma_f32_16x16x32_bf16(wf, xf[ks], acc, 0, 0, 0);
    }
    #pragma unroll
    for (int jj = 0; jj < 4; ++jj) {
      int o = t * 16 + g * 4 + jj;               // D row = channel, D col = pixel c
      short bv16 = bf16s((acc[jj] + bias[o]) * gt);
      if (o < 64) qk_tile[c][o] = bv16;
      else        v_tile[o - 64][c] = bv16;
    }
  }
  __syncthreads();

  int qt32 = nt >> 1, sv = nt & 1;
  // ---- Q/K stores: 128 chunks of 16B (qk, s2, h2, px) ----
  if (tid < 128) {
    int qk = tid >> 6, rem = tid & 63;
    int px = rem & 15, hs = rem >> 4;
    int s2 = hs >> 1, h2 = hs & 1;
    s16x8 chunk = *(const s16x8*)&qk_tile[px][qk * 32 + s2 * 16 + h2 * 8];
    short* dst = qk ? ksz : qs;
    int r = sv * 16 + px;
    *(s16x8*)&dst[((((size_t)b * QG_ + qt32) * 2 + s2) * 64 + h2 * 32 + r) * 8] = chunk;
  }
  // ---- V stores: 512 chunks, 2 per thread; chunk = (ct, h2, lam) ----
  #pragma unroll
  for (int it = 0; it < 2; ++it) {
    int idx = tid + it * 256;
    int lam = idx & 31, cthi = idx >> 5;
    int h2 = cthi & 1, ct = cthi >> 1;
    int ch = ct * 32 + lam;
    unsigned long long lo = *(const unsigned long long*)&v_tile[ch][h2 * 4];
    unsigned long long hq = *(const unsigned long long*)&v_tile[ch][8 + h2 * 4];
    size_t vi = ((((size_t)(b * MB_ + qt32) * 8 + ct) * 2 + sv) * 64 + h2 * 32 + lam) * 8;
    *(unsigned long long*)&vs[vi]     = lo;
    *(unsigned long long*)&vs[vi + 4] = hq;
  }
}

// ---- attn v7 (round-12 best): de-phased 2 blocks/CU, 1 barrier/iter, 4-buffer pipeline ----
// 512 blocks x 256 thr (4 waves). Block: batch b, 4 q-tiles, kv quarter s
// (32 tiles of 32 keys). 4 LDS buffers (72KB): stage j+1 -> buf (j+1)&3,
// QK reads buf j&3, PV reads buf (j-1)&3 (2-iter buffer lifetime => single
// barrier/iter is race-free). Counted vmcnt. Fixed-max softmax.
__global__ __launch_bounds__(256, 2) void attn_split_kernel(
    const short* __restrict__ qs, const short* __restrict__ ksz,
    const short* __restrict__ vs, short* __restrict__ part,
    float* __restrict__ mlbuf) {
  __shared__ __align__(16) short k_lds[4][1024];   // 4 x 2KB
  __shared__ __align__(16) short v_lds[4][8192];   // 4 x 16KB

  int bid = blockIdx.x;
  int b  = (bid & 7) >> 1;                         // batch pinned to XCD pair
  int u  = ((bid >> 3) << 1) | (bid & 1);          // 0..127
  int qb = u >> 2, s = u & 3;
  int tid = threadIdx.x, lane = tid & 63, wave = tid >> 6;
  int lq = lane & 31, hi = lane >> 5;
  int qt = qb * 4 + wave;

  const short* qbp = qs + (size_t)(((b * QG_ + qt) * 2) * 64 + lane) * 8;
  s16x8 qf0 = *(const s16x8*)(qbp);
  s16x8 qf1 = *(const s16x8*)(qbp + 512);
  asm volatile("s_waitcnt vmcnt(0)" ::: "memory");   // zero vm counter

  f32x16 acc[8];
  #pragma unroll
  for (int ct = 0; ct < 8; ++ct)
    #pragma unroll
    for (int e = 0; e < 16; ++e) acc[ct][e] = 0.f;
  float lsum = 0.f;

  const char* kbase = (const char*)(ksz + (size_t)b * (MB_ * 1024));
  const char* vbase = (const char*)(vs + (size_t)b * ((size_t)MB_ * 8192));

  // per-iter loads/wave: V 4 (all waves) + K 1 (tid<128 i.e. waves 0,1) = 5 or 4
  #define STAGE(mb, nb)                                                          \
    {                                                                            \
      const char* vsrc = vbase + (size_t)(mb) * 16384;                           \
      _Pragma("unroll")                                                          \
      for (int r = 0; r < 4; ++r)                                                \
        gl_lds16(vsrc + r * 4096 + tid * 16, &v_lds[nb][r * 2048 + tid * 8]);    \
      if (tid < 128) {                                                           \
        const char* ksrc = kbase + (size_t)(mb) * 2048;                          \
        gl_lds16(ksrc + tid * 16, &k_lds[nb][tid * 8]);                          \
      }                                                                          \
    }
  #define WAIT_PREV()                                                            \
    {                                                                            \
      if (wave < 2) asm volatile("s_waitcnt vmcnt(5)" ::: "memory");             \
      else          asm volatile("s_waitcnt vmcnt(4)" ::: "memory");             \
    }

  s16x8 pf0, pf1;
  f32x16 st;

  #define QKT(buf)                                                               \
    {                                                                            \
      const short* kb = k_lds[buf];                                              \
      s16x8 kf0 = *(const s16x8*)(kb + lane * 8);                                \
      s16x8 kf1 = *(const s16x8*)(kb + 512 + lane * 8);                          \
      _Pragma("unroll")                                                          \
      for (int e = 0; e < 16; ++e) st[e] = 0.f;                                  \
      st = __builtin_amdgcn_mfma_f32_32x32x16_bf16(kf0, qf0, st, 0, 0, 0);       \
      st = __builtin_amdgcn_mfma_f32_32x32x16_bf16(kf1, qf1, st, 0, 0, 0);       \
    }

  #define SOFTMAX()                                                              \
    {                                                                            \
      float psum = 0.f;                                                          \
      _Pragma("unroll")                                                          \
      for (int j = 0; j < 8; ++j) {                                              \
        float p = exp2f((st[j] - MFIX) * LOG2E);                                 \
        psum += p; pf0[j] = bf16s(p);                                            \
      }                                                                          \
      _Pragma("unroll")                                                          \
      for (int j = 0; j < 8; ++j) {                                              \
        float p = exp2f((st[8 + j] - MFIX) * LOG2E);                             \
        psum += p; pf1[j] = bf16s(p);                                            \
      }                                                                          \
      lsum += psum;                                                              \
    }

  #define PVACC(buf)                                                             \
    {                                                                            \
      const short* vb = v_lds[buf];                                              \
      _Pragma("unroll")                                                          \
      for (int ct = 0; ct < 8; ++ct) {                                           \
        s16x8 vf0 = *(const s16x8*)(vb + (ct * 2 + 0) * 512 + lane * 8);         \
        s16x8 vf1 = *(const s16x8*)(vb + (ct * 2 + 1) * 512 + lane * 8);         \
        acc[ct] = __builtin_amdgcn_mfma_f32_32x32x16_bf16(vf0, pf0, acc[ct], 0, 0, 0); \
        acc[ct] = __builtin_amdgcn_mfma_f32_32x32x16_bf16(vf1, pf1, acc[ct], 0, 0, 0); \
      }                                                                          \
    }

  int base = s * 32;
  // ---- prologue: stage batch 0,1; first iter computes P(0) only ----
  STAGE(base + 0, 0);
  {
    STAGE(base + 1, 1);
    WAIT_PREV();
    __builtin_amdgcn_s_barrier();
    QKT(0);
    SOFTMAX();
  }
  for (int j = 1; j < 32; ++j) {
    int jn = (j + 1 > 31) ? 31 : j + 1;    // tail duplicate stage is benign
    STAGE(base + jn, (j + 1) & 3);
    WAIT_PREV();                           // batch j landed; batch j+1 in flight
    __builtin_amdgcn_s_barrier();
    __builtin_amdgcn_s_setprio(1);
    QKT(j & 3);                            // S(j)
    PVACC((j - 1) & 3);                    // O += V(j-1) P(j-1)
    __builtin_amdgcn_s_setprio(0);
    SOFTMAX();                             // P(j)  (overwrites pf after PVACC reads)
  }
  PVACC(31 & 3);                           // epilogue: last PV

  // fold the two half-lanes' key sets once
  lsum += __shfl_xor(lsum, 32);

  // ---- write partial: l (f32) + acc (bf16, [ch][32q]) ----
  int pt = (b * 128 + qt) * 4 + s;
  if (lane < 32) mlbuf[pt * 64 + lq] = lsum;
  short* pb = part + (size_t)pt * 8192;
  #pragma unroll
  for (int ct = 0; ct < 8; ++ct)
    #pragma unroll
    for (int e = 0; e < 16; ++e) {
      int CH = ct * 32 + (e & 3) + 8 * (e >> 2) + 4 * hi;
      pb[CH * 32 + lq] = bf16s(acc[ct][e]);
    }
  #undef STAGE
  #undef WAIT_PREV
  #undef QKT
  #undef SOFTMAX
  #undef PVACC
}

// ------- combine: plain sum over 4 kv-splits (shared fixed max), residual, 2x vectorized ----
__global__ __launch_bounds__(256) void combine_kernel(
    const short* __restrict__ part, const float* __restrict__ mlbuf,
    const float* __restrict__ x, const float* __restrict__ gamma,
    float* __restrict__ out) {
  int bid = blockIdx.x;                 // 512 = 4b x 128qt
  int b = bid >> 7, qt = bid & 127;
  int t = threadIdx.x;
  int qh = t & 15, cg = (t >> 4) & 7, hf = t >> 7;
  int q0 = qh * 2;
  int base = (b * 128 + qt) * 4;
  float L0 = mlbuf[(base + 0) * 64 + q0] + mlbuf[(base + 1) * 64 + q0]
           + mlbuf[(base + 2) * 64 + q0] + mlbuf[(base + 3) * 64 + q0];
  float L1 = mlbuf[(base + 0) * 64 + q0 + 1] + mlbuf[(base + 1) * 64 + q0 + 1]
           + mlbuf[(base + 2) * 64 + q0 + 1] + mlbuf[(base + 3) * 64 + q0 + 1];
  float gmm = gamma[0];
  float rn0 = gmm / L0, rn1 = gmm / L1;
  int n0 = qt * 32 + q0;
  const short* p0 = part + (size_t)(base + 0) * 8192;
  const short* p1 = part + (size_t)(base + 1) * 8192;
  const short* p2 = part + (size_t)(base + 2) * 8192;
  const short* p3 = part + (size_t)(base + 3) * 8192;
  #pragma unroll 4
  for (int cc = 0; cc < 16; ++cc) {
    int ch = cg * 32 + hf * 16 + cc;
    int off = ch * 32 + q0;
    unsigned a0 = *(const unsigned*)&p0[off];
    unsigned a1 = *(const unsigned*)&p1[off];
    unsigned a2 = *(const unsigned*)&p2[off];
    unsigned a3 = *(const unsigned*)&p3[off];
    float o0 = bflo(a0) + bflo(a1) + bflo(a2) + bflo(a3);
    float o1 = bfhi(a0) + bfhi(a1) + bfhi(a2) + bfhi(a3);
    int idx = (b * C_ + ch) * N_ + n0;
    float2 xv = *(const float2*)&x[idx];
    float2 ov;
    ov.x = rn0 * o0 + xv.x;
    ov.y = rn1 * o1 + xv.y;
    *(float2*)&out[idx] = ov;
  }
}

// ---------------- fallback attn (register-V, fixed-max, no workspace partials) --------
__global__ __launch_bounds__(256, 2) void attn_reg_kernel(
    const short* __restrict__ qs, const short* __restrict__ ksz,
    const short* __restrict__ vs, const float* __restrict__ x,
    const float* __restrict__ gamma, float* __restrict__ out) {
  __shared__ float comb_l[4][32];
  __shared__ float sumbuf[4][16][4][64];

  int bid = blockIdx.x;
  int b  = (bid & 7) >> 1;
  int qg = ((bid >> 3) << 1) | (bid & 1);
  int tid = threadIdx.x, lane = tid & 63, wave = tid >> 6;
  int lq = lane & 31;

  const short* qb = qs + (size_t)(((b * QG_ + qg) * 2) * 64 + lane) * 8;
  s16x8 qf0 = *(const s16x8*)(qb);
  s16x8 qf1 = *(const s16x8*)(qb + 512);

  f32x16 acc[8];
  #pragma unroll
  for (int ct = 0; ct < 8; ++ct)
    #pragma unroll
    for (int e = 0; e < 16; ++e) acc[ct][e] = 0.f;
  float lsum = 0.f;

  const short* kb0 = ksz + (size_t)b * (MB_ * 1024) + lane * 8;
  const short* vb0 = vs  + (size_t)b * ((size_t)MB_ * 8192) + lane * 8;

  int mb = wave;
  s16x8 kf0 = *(const s16x8*)(kb0 + mb * 1024);
  s16x8 kf1 = *(const s16x8*)(kb0 + mb * 1024 + 512);

  for (int i = 0; i < 32; ++i) {
    const short* vb = vb0 + (size_t)mb * 8192;
    s16x8 vf[16];
    #pragma unroll
    for (int t = 0; t < 16; ++t) vf[t] = *(const s16x8*)(vb + t * 512);

    f32x16 st;
    #pragma unroll
    for (int e = 0; e < 16; ++e) st[e] = 0.f;
    st = __builtin_amdgcn_mfma_f32_32x32x16_bf16(kf0, qf0, st, 0, 0, 0);
    st = __builtin_amdgcn_mfma_f32_32x32x16_bf16(kf1, qf1, st, 0, 0, 0);

    int mbn = (i < 31) ? (mb + 4) : wave;
    s16x8 nk0 = *(const s16x8*)(kb0 + mbn * 1024);
    s16x8 nk1 = *(const s16x8*)(kb0 + mbn * 1024 + 512);

    float psum = 0.f;
    s16x8 pf0, pf1;
    #pragma unroll
    for (int j = 0; j < 8; ++j) {
      float p = exp2f((st[j] - MFIX) * LOG2E);
      psum += p; pf0[j] = bf16s(p);
    }
    #pragma unroll
    for (int j = 0; j < 8; ++j) {
      float p = exp2f((st[8 + j] - MFIX) * LOG2E);
      psum += p; pf1[j] = bf16s(p);
    }
    lsum += psum;

    #pragma unroll
    for (int ct = 0; ct < 8; ++ct) {
      acc[ct] = __builtin_amdgcn_mfma_f32_32x32x16_bf16(vf[ct * 2],     pf0, acc[ct], 0, 0, 0);
      acc[ct] = __builtin_amdgcn_mfma_f32_32x32x16_bf16(vf[ct * 2 + 1], pf1, acc[ct], 0, 0, 0);
    }
    kf0 = nk0; kf1 = nk1; mb = mbn;
  }

  lsum += __shfl_xor(lsum, 32);
  if (lane < 32) comb_l[wave][lq] = lsum;
  __syncthreads();
  float L = comb_l[0][lq] + comb_l[1][lq] + comb_l[2][lq] + comb_l[3][lq];
  float rn = gamma[0] / L;
  int n = qg * 32 + lq;
  int hi = lane >> 5;

  for (int phase = 0; phase < 2; ++phase) {
    #pragma unroll
    for (int t = 0; t < 4; ++t)
      #pragma unroll
      for (int e = 0; e < 16; ++e)
        sumbuf[t][e][wave][lane] = acc[phase * 4 + t][e];
    __syncthreads();
    int ct = phase * 4 + wave;
    #pragma unroll
    for (int e = 0; e < 16; ++e) {
      float ssum = sumbuf[wave][e][0][lane] + sumbuf[wave][e][1][lane]
                 + sumbuf[wave][e][2][lane] + sumbuf[wave][e][3][lane];
      int ch = ct * 32 + (e & 3) + 8 * (e >> 2) + 4 * hi;
      int idx = (b * C_ + ch) * N_ + n;
      out[idx] = rn * ssum + x[idx];
    }
    __syncthreads();
  }
}

extern "C" void kernel_launch(void* const* d_in, const int* in_sizes, int n_in,
                              void* d_out, int out_size, void* d_ws, size_t ws_size,
                              hipStream_t stream) {
  const float* x     = (const float*)d_in[0];
  const float* gm    = (const float*)d_in[1];
  const float* Wq    = (const float*)d_in[2];
  const float* bq    = (const float*)d_in[3];
  const float* Wk    = (const float*)d_in[4];
  const float* bk    = (const float*)d_in[5];
  const float* Wv    = (const float*)d_in[6];
  const float* bv    = (const float*)d_in[7];
  const float* gamma = (const float*)d_in[8];

  char*  ws    = (char*)d_ws;
  short* wfrag = (short*)(ws + WS_WFRAG);
  float* bias  = (float*)(ws + WS_BIAS);
  short* qs    = (short*)(ws + WS_Q);
  short* ksz   = (short*)(ws + WS_K);
  short* vs    = (short*)(ws + WS_V);
  float* out   = (float*)d_out;

  wprep_kernel<<<dim3(320), dim3(256), 0, stream>>>(Wq, Wk, Wv, bq, bk, bv, wfrag, bias);
  proj_kernel<<<dim3(1024), dim3(256), 0, stream>>>(x, wfrag, bias, gm, qs, ksz, vs);

  if (ws_size >= WS_NEED) {
    short* part  = (short*)(ws + WS_PART);
    float* mlbuf = (float*)(ws + WS_ML);
    attn_split_kernel<<<dim3(512), dim3(256), 0, stream>>>(qs, ksz, vs, part, mlbuf);
    combine_kernel<<<dim3(512), dim3(256), 0, stream>>>(part, mlbuf, x, gamma, out);
  } else {
    attn_reg_kernel<<<dim3(512), dim3(256), 0, stream>>>(qs, ksz, vs, x, gamma, out);
  }
}

// Round 17
// 83.099 us; speedup vs baseline: 1.2054x; 1.0392x over previous
//
#include <hip/hip_runtime.h>
#include <hip/hip_bf16.h>
#include <cstdint>

typedef __attribute__((ext_vector_type(4)))  float f32x4;
typedef __attribute__((ext_vector_type(16))) float f32x16;
typedef __attribute__((ext_vector_type(8)))  short s16x8;

#define LOG2E 1.4426950408889634f
#define MFIX  64.0f              // fixed softmax max: exp(S-64); safe for S in (-23, 152)

#define B_   4
#define C_   256
#define N_   4096
#define NT_  256
#define MB_  128
#define QG_  128

// workspace byte offsets
#define WS_WFRAG 0u
#define WS_BIAS  163840u
#define WS_Q     262144u
#define WS_K     1310720u
#define WS_V     2359296u
#define WS_PART  11534336u   // 512 qtiles * 4 splits * 8192 bf16 = 32 MiB
#define WS_ML    45088768u   // 2048 * 64 f32
#define WS_NEED  45613056ull

__device__ __forceinline__ short bf16s(float f) {
  return (short)__bfloat16_as_ushort(__float2bfloat16(f));
}
__device__ __forceinline__ float bf2f(short h) {
  union { unsigned u; float f; } v; v.u = ((unsigned)(unsigned short)h) << 16;
  return v.f;
}
__device__ __forceinline__ void gl_lds16(const void* g, void* l) {
  __builtin_amdgcn_global_load_lds(
      (const __attribute__((address_space(1))) unsigned int*)g,
      (__attribute__((address_space(3))) unsigned int*)l, 16, 0, 0);
}

// ---------------- pack W (320x256) into A-frag layout (16x16x32), gather bias ----------------
__global__ void wprep_kernel(const float* __restrict__ Wq, const float* __restrict__ Wk,
                             const float* __restrict__ Wv, const float* __restrict__ bq,
                             const float* __restrict__ bk, const float* __restrict__ bv,
                             short* __restrict__ wfrag, float* __restrict__ bias) {
  int d0 = blockIdx.x * 256 + threadIdx.x;
  int d = d0;
  int j  = d & 7;  d >>= 3;
  int c  = d & 15; d >>= 4;
  int g  = d & 3;  d >>= 2;
  int ks = d & 7;  d >>= 3;
  int t  = d;
  int o  = t * 16 + c;
  int ch = ks * 32 + g * 8 + j;
  float w = (o < 32) ? Wq[o * 256 + ch] : (o < 64) ? Wk[(o - 32) * 256 + ch]
                                                   : Wv[(o - 64) * 256 + ch];
  wfrag[d0] = bf16s(w);
  if (d0 < 320) bias[d0] = (d0 < 32) ? bq[d0] : (d0 < 64) ? bk[d0 - 32] : bv[d0 - 64];
}

// ------- fused QKV projection: LDS-staged coalesced x loads + MFMA + gate + swizzled stores ----
// Per block (b, nt): stage x-tile [256ch][16px] via float4 rows (4 loads/thread),
// convert to bf16 into transposed xt[16][264]; fragments = 8x ds_read_b128/thread.
__global__ __launch_bounds__(256) void proj_kernel(
    const float* __restrict__ x, const short* __restrict__ wfrag,
    const float* __restrict__ bias, const float* __restrict__ gm,
    short* __restrict__ qs, short* __restrict__ ksz, short* __restrict__ vs) {
  __shared__ __align__(16) short xt[16][264];   // [px][ch], +8 pad (row +4 banks)

  int b = blockIdx.x >> 8, nt = blockIdx.x & 255;
  int tid = threadIdx.x;
  int lane = tid & 63, wave = tid >> 6;
  int g = lane >> 4, c = lane & 15;
  int n = nt * 16 + c;

  // inline gate: bilinear align-corners 32->64 + sigmoid
  float gt;
  {
    int y = n >> 6, xp = n & 63;
    float fy = (float)(y * 31) / 63.0f;
    float fx = (float)(xp * 31) / 63.0f;
    int y0 = (int)fy, x0 = (int)fx;
    float wy = fy - (float)y0, wx = fx - (float)x0;
    int y1 = min(y0 + 1, 31), x1 = min(x0 + 1, 31);
    const float* p = gm + b * 1024;
    float v00 = p[y0 * 32 + x0], v01 = p[y0 * 32 + x1];
    float v10 = p[y1 * 32 + x0], v11 = p[y1 * 32 + x1];
    float top = v00 * (1.f - wx) + v01 * wx;
    float bot = v10 * (1.f - wx) + v11 * wx;
    float gv  = top * (1.f - wy) + bot * wy;
    gt = 1.0f + 1.0f / (1.0f + expf(-gv));
  }

  // ---- stage x tile: 1024 float4 tasks (ch row, pixel-quad), 4 per thread ----
  {
    const float* xb0 = x + (size_t)b * (C_ * N_) + nt * 16;
    int pq = tid & 3, chb = tid >> 2;          // pixel quad 0..3, ch 0..63
    #pragma unroll
    for (int k = 0; k < 4; ++k) {
      int ch = chb + k * 64;
      float4 v4 = *(const float4*)(xb0 + (size_t)ch * N_ + pq * 4);
      xt[pq * 4 + 0][ch] = bf16s(v4.x);
      xt[pq * 4 + 1][ch] = bf16s(v4.y);
      xt[pq * 4 + 2][ch] = bf16s(v4.z);
      xt[pq * 4 + 3][ch] = bf16s(v4.w);
    }
  }
  __syncthreads();

  // B-fragments: lane (g,c) elem j = x[ks*32+g*8+j][n]  -> 8x ds_read_b128
  s16x8 xf[8];
  #pragma unroll
  for (int ks = 0; ks < 8; ++ks)
    xf[ks] = *(const s16x8*)&xt[c][ks * 32 + g * 8];

  int qt32 = n >> 5, r = n & 31;
  for (int t = wave * 5; t < wave * 5 + 5; ++t) {
    f32x4 acc = {0.f, 0.f, 0.f, 0.f};
    #pragma unroll
    for (int ks = 0; ks < 8; ++ks) {
      s16x8 wf = *(const s16x8*)(wfrag + ((((t * 8 + ks) * 4 + g) * 16 + c) * 8));
      acc = __builtin_amdgcn_mfma_f32_16x16x32_bf16(wf, xf[ks], acc, 0, 0, 0);
    }
    #pragma unroll
    for (int jj = 0; jj < 4; ++jj) {
      int o = t * 16 + g * 4 + jj;
      float val = (acc[jj] + bias[o]) * gt;
      short bv16 = bf16s(val);
      if (o < 64) {
        int ch = o & 31;
        int s  = (ch >> 4) & 1, hi = (ch >> 3) & 1, j = ch & 7;
        short* dst = (o < 32) ? qs : ksz;
        dst[(((b * QG_ + qt32) * 2 + s) * 64 + hi * 32 + r) * 8 + j] = bv16;
      } else {
        int cv = o - 64;
        int ct = cv >> 5, lam = cv & 31;
        int s  = (r >> 4) & 1, r4 = r & 15;
        int k  = (r4 & 3) | (((r4 >> 3) & 1) << 2) | (((r4 >> 2) & 1) << 3);
        int hi = k >> 3, j = k & 7;
        vs[((((size_t)(b * MB_ + qt32) * 8 + ct) * 2 + s) * 64 + hi * 32 + lam) * 8 + j] = bv16;
      }
    }
  }
}

// ---- attn v7 (round-12 best): de-phased 2 blocks/CU, 1 barrier/iter, 4-buffer pipeline ----
__global__ __launch_bounds__(256, 2) void attn_split_kernel(
    const short* __restrict__ qs, const short* __restrict__ ksz,
    const short* __restrict__ vs, short* __restrict__ part,
    float* __restrict__ mlbuf) {
  __shared__ __align__(16) short k_lds[4][1024];   // 4 x 2KB
  __shared__ __align__(16) short v_lds[4][8192];   // 4 x 16KB

  int bid = blockIdx.x;
  int b  = (bid & 7) >> 1;                         // batch pinned to XCD pair
  int u  = ((bid >> 3) << 1) | (bid & 1);          // 0..127
  int qb = u >> 2, s = u & 3;
  int tid = threadIdx.x, lane = tid & 63, wave = tid >> 6;
  int lq = lane & 31, hi = lane >> 5;
  int qt = qb * 4 + wave;

  const short* qbp = qs + (size_t)(((b * QG_ + qt) * 2) * 64 + lane) * 8;
  s16x8 qf0 = *(const s16x8*)(qbp);
  s16x8 qf1 = *(const s16x8*)(qbp + 512);
  asm volatile("s_waitcnt vmcnt(0)" ::: "memory");   // zero vm counter

  f32x16 acc[8];
  #pragma unroll
  for (int ct = 0; ct < 8; ++ct)
    #pragma unroll
    for (int e = 0; e < 16; ++e) acc[ct][e] = 0.f;
  float lsum = 0.f;

  const char* kbase = (const char*)(ksz + (size_t)b * (MB_ * 1024));
  const char* vbase = (const char*)(vs + (size_t)b * ((size_t)MB_ * 8192));

  // per-iter loads/wave: V 4 (all waves) + K 1 (tid<128 i.e. waves 0,1) = 5 or 4
  #define STAGE(mb, nb)                                                          \
    {                                                                            \
      const char* vsrc = vbase + (size_t)(mb) * 16384;                           \
      _Pragma("unroll")                                                          \
      for (int r = 0; r < 4; ++r)                                                \
        gl_lds16(vsrc + r * 4096 + tid * 16, &v_lds[nb][r * 2048 + tid * 8]);    \
      if (tid < 128) {                                                           \
        const char* ksrc = kbase + (size_t)(mb) * 2048;                          \
        gl_lds16(ksrc + tid * 16, &k_lds[nb][tid * 8]);                          \
      }                                                                          \
    }
  #define WAIT_PREV()                                                            \
    {                                                                            \
      if (wave < 2) asm volatile("s_waitcnt vmcnt(5)" ::: "memory");             \
      else          asm volatile("s_waitcnt vmcnt(4)" ::: "memory");             \
    }

  s16x8 pf0, pf1;
  f32x16 st;

  #define QKT(buf)                                                               \
    {                                                                            \
      const short* kb = k_lds[buf];                                              \
      s16x8 kf0 = *(const s16x8*)(kb + lane * 8);                                \
      s16x8 kf1 = *(const s16x8*)(kb + 512 + lane * 8);                          \
      _Pragma("unroll")                                                          \
      for (int e = 0; e < 16; ++e) st[e] = 0.f;                                  \
      st = __builtin_amdgcn_mfma_f32_32x32x16_bf16(kf0, qf0, st, 0, 0, 0);       \
      st = __builtin_amdgcn_mfma_f32_32x32x16_bf16(kf1, qf1, st, 0, 0, 0);       \
    }

  #define SOFTMAX()                                                              \
    {                                                                            \
      float psum = 0.f;                                                          \
      _Pragma("unroll")                                                          \
      for (int j = 0; j < 8; ++j) {                                              \
        float p = exp2f((st[j] - MFIX) * LOG2E);                                 \
        psum += p; pf0[j] = bf16s(p);                                            \
      }                                                                          \
      _Pragma("unroll")                                                          \
      for (int j = 0; j < 8; ++j) {                                              \
        float p = exp2f((st[8 + j] - MFIX) * LOG2E);                             \
        psum += p; pf1[j] = bf16s(p);                                            \
      }                                                                          \
      lsum += psum;                                                              \
    }

  #define PVACC(buf)                                                             \
    {                                                                            \
      const short* vb = v_lds[buf];                                              \
      _Pragma("unroll")                                                          \
      for (int ct = 0; ct < 8; ++ct) {                                           \
        s16x8 vf0 = *(const s16x8*)(vb + (ct * 2 + 0) * 512 + lane * 8);         \
        s16x8 vf1 = *(const s16x8*)(vb + (ct * 2 + 1) * 512 + lane * 8);         \
        acc[ct] = __builtin_amdgcn_mfma_f32_32x32x16_bf16(vf0, pf0, acc[ct], 0, 0, 0); \
        acc[ct] = __builtin_amdgcn_mfma_f32_32x32x16_bf16(vf1, pf1, acc[ct], 0, 0, 0); \
      }                                                                          \
    }

  int base = s * 32;
  // ---- prologue: stage batch 0,1; first iter computes P(0) only ----
  STAGE(base + 0, 0);
  {
    STAGE(base + 1, 1);
    WAIT_PREV();
    __builtin_amdgcn_s_barrier();
    QKT(0);
    SOFTMAX();
  }
  for (int j = 1; j < 32; ++j) {
    int jn = (j + 1 > 31) ? 31 : j + 1;    // tail duplicate stage is benign
    STAGE(base + jn, (j + 1) & 3);
    WAIT_PREV();                           // batch j landed; batch j+1 in flight
    __builtin_amdgcn_s_barrier();
    __builtin_amdgcn_s_setprio(1);
    QKT(j & 3);                            // S(j)
    PVACC((j - 1) & 3);                    // O += V(j-1) P(j-1)
    __builtin_amdgcn_s_setprio(0);
    SOFTMAX();                             // P(j)  (overwrites pf after PVACC reads)
  }
  PVACC(31 & 3);                           // epilogue: last PV

  // fold the two half-lanes' key sets once
  lsum += __shfl_xor(lsum, 32);

  // ---- write partial: l (f32) + acc (bf16, [ch][32q]) ----
  int pt = (b * 128 + qt) * 4 + s;
  if (lane < 32) mlbuf[pt * 64 + lq] = lsum;
  short* pb = part + (size_t)pt * 8192;
  #pragma unroll
  for (int ct = 0; ct < 8; ++ct)
    #pragma unroll
    for (int e = 0; e < 16; ++e) {
      int CH = ct * 32 + (e & 3) + 8 * (e >> 2) + 4 * hi;
      pb[CH * 32 + lq] = bf16s(acc[ct][e]);
    }
  #undef STAGE
  #undef WAIT_PREV
  #undef QKT
  #undef SOFTMAX
  #undef PVACC
}

// ---------------- combine: plain sum over 4 kv-splits (shared fixed max), residual ----------
__global__ __launch_bounds__(256) void combine_kernel(
    const short* __restrict__ part, const float* __restrict__ mlbuf,
    const float* __restrict__ x, const float* __restrict__ gamma,
    float* __restrict__ out) {
  int bid = blockIdx.x;
  int b = bid >> 7, qt = bid & 127;
  int t = threadIdx.x;
  int q = t & 31, cg = t >> 5;
  int base = (b * 128 + qt) * 4;
  float L = mlbuf[(base + 0) * 64 + q] + mlbuf[(base + 1) * 64 + q]
          + mlbuf[(base + 2) * 64 + q] + mlbuf[(base + 3) * 64 + q];
  float rn = gamma[0] / L;
  int n = qt * 32 + q;
  const short* p0 = part + (size_t)(base + 0) * 8192;
  const short* p1 = part + (size_t)(base + 1) * 8192;
  const short* p2 = part + (size_t)(base + 2) * 8192;
  const short* p3 = part + (size_t)(base + 3) * 8192;
  #pragma unroll 4
  for (int cc = 0; cc < 32; ++cc) {
    int ch = cg * 32 + cc;
    int off = ch * 32 + q;
    float o = bf2f(p0[off]) + bf2f(p1[off]) + bf2f(p2[off]) + bf2f(p3[off]);
    int idx = (b * C_ + ch) * N_ + n;
    out[idx] = rn * o + x[idx];
  }
}

// ---------------- fallback attn (register-V, fixed-max, no workspace partials) --------
__global__ __launch_bounds__(256, 2) void attn_reg_kernel(
    const short* __restrict__ qs, const short* __restrict__ ksz,
    const short* __restrict__ vs, const float* __restrict__ x,
    const float* __restrict__ gamma, float* __restrict__ out) {
  __shared__ float comb_l[4][32];
  __shared__ float sumbuf[4][16][4][64];

  int bid = blockIdx.x;
  int b  = (bid & 7) >> 1;
  int qg = ((bid >> 3) << 1) | (bid & 1);
  int tid = threadIdx.x, lane = tid & 63, wave = tid >> 6;
  int lq = lane & 31;

  const short* qb = qs + (size_t)(((b * QG_ + qg) * 2) * 64 + lane) * 8;
  s16x8 qf0 = *(const s16x8*)(qb);
  s16x8 qf1 = *(const s16x8*)(qb + 512);

  f32x16 acc[8];
  #pragma unroll
  for (int ct = 0; ct < 8; ++ct)
    #pragma unroll
    for (int e = 0; e < 16; ++e) acc[ct][e] = 0.f;
  float lsum = 0.f;

  const short* kb0 = ksz + (size_t)b * (MB_ * 1024) + lane * 8;
  const short* vb0 = vs  + (size_t)b * ((size_t)MB_ * 8192) + lane * 8;

  int mb = wave;
  s16x8 kf0 = *(const s16x8*)(kb0 + mb * 1024);
  s16x8 kf1 = *(const s16x8*)(kb0 + mb * 1024 + 512);

  for (int i = 0; i < 32; ++i) {
    const short* vb = vb0 + (size_t)mb * 8192;
    s16x8 vf[16];
    #pragma unroll
    for (int t = 0; t < 16; ++t) vf[t] = *(const s16x8*)(vb + t * 512);

    f32x16 st;
    #pragma unroll
    for (int e = 0; e < 16; ++e) st[e] = 0.f;
    st = __builtin_amdgcn_mfma_f32_32x32x16_bf16(kf0, qf0, st, 0, 0, 0);
    st = __builtin_amdgcn_mfma_f32_32x32x16_bf16(kf1, qf1, st, 0, 0, 0);

    int mbn = (i < 31) ? (mb + 4) : wave;
    s16x8 nk0 = *(const s16x8*)(kb0 + mbn * 1024);
    s16x8 nk1 = *(const s16x8*)(kb0 + mbn * 1024 + 512);

    float psum = 0.f;
    s16x8 pf0, pf1;
    #pragma unroll
    for (int j = 0; j < 8; ++j) {
      float p = exp2f((st[j] - MFIX) * LOG2E);
      psum += p; pf0[j] = bf16s(p);
    }
    #pragma unroll
    for (int j = 0; j < 8; ++j) {
      float p = exp2f((st[8 + j] - MFIX) * LOG2E);
      psum += p; pf1[j] = bf16s(p);
    }
    lsum += psum;

    #pragma unroll
    for (int ct = 0; ct < 8; ++ct) {
      acc[ct] = __builtin_amdgcn_mfma_f32_32x32x16_bf16(vf[ct * 2],     pf0, acc[ct], 0, 0, 0);
      acc[ct] = __builtin_amdgcn_mfma_f32_32x32x16_bf16(vf[ct * 2 + 1], pf1, acc[ct], 0, 0, 0);
    }
    kf0 = nk0; kf1 = nk1; mb = mbn;
  }

  lsum += __shfl_xor(lsum, 32);
  if (lane < 32) comb_l[wave][lq] = lsum;
  __syncthreads();
  float L = comb_l[0][lq] + comb_l[1][lq] + comb_l[2][lq] + comb_l[3][lq];
  float rn = gamma[0] / L;
  int n = qg * 32 + lq;
  int hi = lane >> 5;

  for (int phase = 0; phase < 2; ++phase) {
    #pragma unroll
    for (int t = 0; t < 4; ++t)
      #pragma unroll
      for (int e = 0; e < 16; ++e)
        sumbuf[t][e][wave][lane] = acc[phase * 4 + t][e];
    __syncthreads();
    int ct = phase * 4 + wave;
    #pragma unroll
    for (int e = 0; e < 16; ++e) {
      float ssum = sumbuf[wave][e][0][lane] + sumbuf[wave][e][1][lane]
                 + sumbuf[wave][e][2][lane] + sumbuf[wave][e][3][lane];
      int ch = ct * 32 + (e & 3) + 8 * (e >> 2) + 4 * hi;
      int idx = (b * C_ + ch) * N_ + n;
      out[idx] = rn * ssum + x[idx];
    }
    __syncthreads();
  }
}

extern "C" void kernel_launch(void* const* d_in, const int* in_sizes, int n_in,
                              void* d_out, int out_size, void* d_ws, size_t ws_size,
                              hipStream_t stream) {
  const float* x     = (const float*)d_in[0];
  const float* gm    = (const float*)d_in[1];
  const float* Wq    = (const float*)d_in[2];
  const float* bq    = (const float*)d_in[3];
  const float* Wk    = (const float*)d_in[4];
  const float* bk    = (const float*)d_in[5];
  const float* Wv    = (const float*)d_in[6];
  const float* bv    = (const float*)d_in[7];
  const float* gamma = (const float*)d_in[8];

  char*  ws    = (char*)d_ws;
  short* wfrag = (short*)(ws + WS_WFRAG);
  float* bias  = (float*)(ws + WS_BIAS);
  short* qs    = (short*)(ws + WS_Q);
  short* ksz   = (short*)(ws + WS_K);
  short* vs    = (short*)(ws + WS_V);
  float* out   = (float*)d_out;

  wprep_kernel<<<dim3(320), dim3(256), 0, stream>>>(Wq, Wk, Wv, bq, bk, bv, wfrag, bias);
  proj_kernel<<<dim3(1024), dim3(256), 0, stream>>>(x, wfrag, bias, gm, qs, ksz, vs);

  if (ws_size >= WS_NEED) {
    short* part  = (short*)(ws + WS_PART);
    float* mlbuf = (float*)(ws + WS_ML);
    attn_split_kernel<<<dim3(512), dim3(256), 0, stream>>>(qs, ksz, vs, part, mlbuf);
    combine_kernel<<<dim3(512), dim3(256), 0, stream>>>(part, mlbuf, x, gamma, out);
  } else {
    attn_reg_kernel<<<dim3(512), dim3(256), 0, stream>>>(qs, ksz, vs, x, gamma, out);
  }
}